// Round 6
// baseline (309.535 us; speedup 1.0000x reference)
//
#include <hip/hip_runtime.h>

#define NCOMP 8
#define NCONT 56
#define NCAT 8
#define NU 100
#define NROWS 32768
#define SEPC 1e-3f
#define T1F 10.0f

// native type of __builtin_amdgcn_cvt_pkrtz / __builtin_amdgcn_fdot2 operands
typedef __fp16 f16x2 __attribute__((ext_vector_type(2)));
// arithmetic-friendly fp16 pair for the packed butterfly add
typedef _Float16 h2arith __attribute__((ext_vector_type(2)));

// One combined weight array: per feature f (0..55), 35 float4 "roles":
//  role 2c+t      : Wh comp c, k=8t..8t+7   (16 roles)
//  role 16+2c+t   : Wv comp c, k=8t..8t+7   (16 roles)
//  role 32+t      : Wic,       k=8t..8t+7   (2 roles)
//  role 34        : pad
#define FSTRIDE 35

union H8 { f16x2 h2[4]; float4 f4; };

__device__ __forceinline__ float sp(float x) {
    // softplus = ln2 * log2(1 + 2^(x*log2e)) via v_exp_f32/v_log_f32
    return 0.69314718f * __builtin_amdgcn_logf(1.0f + __builtin_amdgcn_exp2f(x * 1.44269504f));
}

__device__ __forceinline__ f16x2 pkrtz(float a, float b) {
    return __builtin_amdgcn_cvt_pkrtz(a, b);
}

__device__ __forceinline__ float fdot2(f16x2 a, f16x2 b, float c) {
    return __builtin_amdgcn_fdot2(a, b, c, false);
}

__device__ __forceinline__ h2arith h2shfl_xor(h2arith v, int off) {
    int i = __builtin_bit_cast(int, v);
    i = __shfl_xor(i, off, 64);
    return __builtin_bit_cast(h2arith, i);
}

__global__ __launch_bounds__(512, 8) void tpm_kernel(
    const float* __restrict__ B, const float* __restrict__ Bcat,
    const float* __restrict__ Wh, const float* __restrict__ Whc, const float* __restrict__ bh,
    const float* __restrict__ Wv, const float* __restrict__ Wvc, const float* __restrict__ bv,
    const float* __restrict__ Wic, const float* __restrict__ Wicc, const float* __restrict__ bic,
    float* __restrict__ out)
{
    __shared__ float4 sW[NCONT * FSTRIDE];  // 31360 B, f16 weights (H|V|IC)
    __shared__ float2 sBias[NCOMP];         // (sp(bh), sp(bv))
    __shared__ float  sBic;
    __shared__ int    sCode[8][8][NCAT];    // [wave][local row][cat feature]

    const int tid = threadIdx.x;

    // ---- stage Wh/Wv as f16: idx in [0,896) handles (icp = i*8+c, t) ----
    for (int idx = tid; idx < 896; idx += 512) {
        int icp = idx % 448, t = idx / 448;
        int i = icp >> 3, c = icp & 7;
        const float* gh = Wh + (size_t)(8 * t) * 448 + icp;
        const float* gv = Wv + (size_t)(8 * t) * 448 + icp;
        H8 uh, uv;
#pragma unroll
        for (int p = 0; p < 4; ++p) {
            uh.h2[p] = pkrtz(gh[(2 * p) * 448], gh[(2 * p + 1) * 448]);
            uv.h2[p] = pkrtz(gv[(2 * p) * 448], gv[(2 * p + 1) * 448]);
        }
        sW[i * FSTRIDE + 2 * c + t] = uh.f4;
        sW[i * FSTRIDE + 16 + 2 * c + t] = uv.f4;
    }
    if (tid < 112) {
        int i = tid % 56, t = tid / 56;
        const float* gi = Wic + (size_t)(8 * t) * 56 + i;
        H8 u;
#pragma unroll
        for (int p = 0; p < 4; ++p)
            u.h2[p] = pkrtz(gi[(2 * p) * 56], gi[(2 * p + 1) * 56]);
        sW[i * FSTRIDE + 32 + t] = u.f4;
    }
    if (tid < NCOMP) sBias[tid] = make_float2(sp(bh[tid]), sp(bv[tid]));
    if (tid == NCOMP) sBic = bic[0];
    __syncthreads();

    const int lane = tid & 63;
    const int widx = tid >> 6;      // 0..7
    const int s = lane & 15;        // sublane: feature group
    const int g = lane >> 4;        // row group 0..3
    const int R0 = ((blockIdx.x << 3) + widx) << 3;   // 8 rows per wave, exact cover
    const int rA = R0 + g;          // this group's first row
    const int rB = R0 + 4 + g;      // this group's second row

    // ---- full-wave cooperative one-hot scan of 8 rows ----
    {
        const float4* pc = (const float4*)(Bcat + (size_t)R0 * 800);
#pragma unroll
        for (int it = 0; it < 25; ++it) {
            int idx = it * 64 + lane;           // 0..1599
            int row = idx / 200;
            int pos = idx - row * 200;          // float4 within row
            float4 q = pc[row * 200 + pos];
            float n = (float)(4 * pos);
            float sc = q.x * (n + 1.0f) + q.y * (n + 2.0f) + q.z * (n + 3.0f) + q.w * (n + 4.0f);
            if (sc > 0.5f) {
                int p = (int)sc - 1;            // element within row's 800
                int f = p / NU;
                sCode[widx][row][f] = p - f * NU;
            }
        }
    }
    __threadfence_block();

    // ---- accumulators: 17 channels x 2 rows ----
    float shA[NCOMP], swA[NCOMP], shB[NCOMP], swB[NCOMP];
    float icA = 0.0f, icB = 0.0f;
#pragma unroll
    for (int c = 0; c < NCOMP; ++c) { shA[c] = swA[c] = shB[c] = swB[c] = 0.0f; }

    // ---- 4 passes: lane handles features s, s+16, s+32, s+48 ----
#pragma unroll 1
    for (int j = 0; j < 4; ++j) {
        int f = s + 16 * j;
        if (f < NCONT) {
            // continuous feature: basis for 2 rows, dots against LDS weights
            const float4* pA = (const float4*)(B + (size_t)rA * 896 + f * 16);
            const float4* pB = (const float4*)(B + (size_t)rB * 896 + f * 16);
            float4 a0 = pA[0], a1 = pA[1], a2 = pA[2], a3 = pA[3];
            float4 b0 = pB[0], b1 = pB[1], b2 = pB[2], b3 = pB[3];
            f16x2 baA[8], baB[8];
            baA[0] = pkrtz(a0.x, a0.y); baA[1] = pkrtz(a0.z, a0.w);
            baA[2] = pkrtz(a1.x, a1.y); baA[3] = pkrtz(a1.z, a1.w);
            baA[4] = pkrtz(a2.x, a2.y); baA[5] = pkrtz(a2.z, a2.w);
            baA[6] = pkrtz(a3.x, a3.y); baA[7] = pkrtz(a3.z, a3.w);
            baB[0] = pkrtz(b0.x, b0.y); baB[1] = pkrtz(b0.z, b0.w);
            baB[2] = pkrtz(b1.x, b1.y); baB[3] = pkrtz(b1.z, b1.w);
            baB[4] = pkrtz(b2.x, b2.y); baB[5] = pkrtz(b2.z, b2.w);
            baB[6] = pkrtz(b3.x, b3.y); baB[7] = pkrtz(b3.z, b3.w);

            const float4* pw = sW + f * FSTRIDE;
#pragma unroll
            for (int c = 0; c < NCOMP; ++c) {
                H8 u0, u1, v0, v1;
                u0.f4 = pw[2 * c];      u1.f4 = pw[2 * c + 1];
                v0.f4 = pw[16 + 2 * c]; v1.f4 = pw[17 + 2 * c];
                float hA = 0.0f, hB = 0.0f, vA = 0.0f, vB = 0.0f;
#pragma unroll
                for (int p = 0; p < 4; ++p) {
                    hA = fdot2(baA[p], u0.h2[p], hA);
                    hB = fdot2(baB[p], u0.h2[p], hB);
                    vA = fdot2(baA[p], v0.h2[p], vA);
                    vB = fdot2(baB[p], v0.h2[p], vB);
                }
#pragma unroll
                for (int p = 0; p < 4; ++p) {
                    hA = fdot2(baA[4 + p], u1.h2[p], hA);
                    hB = fdot2(baB[4 + p], u1.h2[p], hB);
                    vA = fdot2(baA[4 + p], v1.h2[p], vA);
                    vB = fdot2(baB[4 + p], v1.h2[p], vB);
                }
                shA[c] += sp(hA); shB[c] += sp(hB);
                swA[c] += sp(vA); swB[c] += sp(vB);
            }
            {
                H8 i0, i1;
                i0.f4 = pw[32]; i1.f4 = pw[33];
                float iA = 0.0f, iB = 0.0f;
#pragma unroll
                for (int p = 0; p < 4; ++p) {
                    iA = fdot2(baA[p], i0.h2[p], iA);
                    iB = fdot2(baB[p], i0.h2[p], iB);
                }
#pragma unroll
                for (int p = 0; p < 4; ++p) {
                    iA = fdot2(baA[4 + p], i1.h2[p], iA);
                    iB = fdot2(baB[4 + p], i1.h2[p], iB);
                }
                icA += iA; icB += iB;   // IC has no softplus
            }
        } else {
            // categorical feature (pass 3, sublanes 8..15): fi = s-8
            int fi = s - 8;
            int cA = sCode[widx][g][fi];
            int cB = sCode[widx][4 + g][fi];
            int gA = fi * NU + cA;
            int gB = fi * NU + cB;
            const float4* qhA = (const float4*)(Whc + gA * 8);
            const float4* qvA = (const float4*)(Wvc + gA * 8);
            const float4* qhB = (const float4*)(Whc + gB * 8);
            const float4* qvB = (const float4*)(Wvc + gB * 8);
            float4 h0 = qhA[0], h1 = qhA[1], v0 = qvA[0], v1 = qvA[1];
            shA[0] += sp(h0.x); shA[1] += sp(h0.y); shA[2] += sp(h0.z); shA[3] += sp(h0.w);
            shA[4] += sp(h1.x); shA[5] += sp(h1.y); shA[6] += sp(h1.z); shA[7] += sp(h1.w);
            swA[0] += sp(v0.x); swA[1] += sp(v0.y); swA[2] += sp(v0.z); swA[3] += sp(v0.w);
            swA[4] += sp(v1.x); swA[5] += sp(v1.y); swA[6] += sp(v1.z); swA[7] += sp(v1.w);
            icA += Wicc[gA];
            float4 h2 = qhB[0], h3 = qhB[1], v2 = qvB[0], v3 = qvB[1];
            shB[0] += sp(h2.x); shB[1] += sp(h2.y); shB[2] += sp(h2.z); shB[3] += sp(h2.w);
            shB[4] += sp(h3.x); shB[5] += sp(h3.y); shB[6] += sp(h3.z); shB[7] += sp(h3.w);
            swB[0] += sp(v2.x); swB[1] += sp(v2.y); swB[2] += sp(v2.z); swB[3] += sp(v2.w);
            swB[4] += sp(v3.x); swB[5] += sp(v3.y); swB[6] += sp(v3.z); swB[7] += sp(v3.w);
            icB += Wicc[gB];
        }
    }

    // ---- pack and 4-step butterfly within each 16-lane group ----
    h2arith hwA[NCOMP], hwB[NCOMP];
#pragma unroll
    for (int c = 0; c < NCOMP; ++c) {
        hwA[c] = __builtin_bit_cast(h2arith, pkrtz(shA[c], swA[c]));
        hwB[c] = __builtin_bit_cast(h2arith, pkrtz(shB[c], swB[c]));
    }
#pragma unroll
    for (int off = 8; off >= 1; off >>= 1) {
#pragma unroll
        for (int c = 0; c < NCOMP; ++c) {
            hwA[c] = hwA[c] + h2shfl_xor(hwA[c], off);
            hwB[c] = hwB[c] + h2shfl_xor(hwB[c], off);
        }
        icA += __shfl_xor(icA, off, 64);
        icB += __shfl_xor(icB, off, 64);
    }

    // ---- sublanes 0..8 emit (t, x) for both rows ----
    if (s < 9) {
        int m = (s == 8) ? 7 : s;
        float tA = SEPC * (float)s, tB = tA;
        float xA = icA + sBic, xB = icB + sBic;
#pragma unroll
        for (int c = 0; c < NCOMP; ++c) {
            float2 bb2 = sBias[c];
            if (c < m) {
                tA += (float)hwA[c][0] + bb2.x;
                tB += (float)hwB[c][0] + bb2.x;
            }
            if (c < s) {
                float vA = (float)hwA[c][1] + bb2.y;
                float vB = (float)hwB[c][1] + bb2.y;
                xA += (c & 1) ? -vA : vA;
                xB += (c & 1) ? -vB : vB;
            }
        }
        if (s == 8) { tA = fmaxf(tA, T1F); tB = fmaxf(tB, T1F); }
        float2 oA; oA.x = tA; oA.y = xA;
        float2 oB; oB.x = tB; oB.y = xB;
        ((float2*)out)[(size_t)rA * 9 + s] = oA;
        ((float2*)out)[(size_t)rB * 9 + s] = oB;
    }
}

extern "C" void kernel_launch(void* const* d_in, const int* in_sizes, int n_in,
                              void* d_out, int out_size, void* d_ws, size_t ws_size,
                              hipStream_t stream) {
    (void)in_sizes; (void)n_in; (void)out_size; (void)d_ws; (void)ws_size;
    const float* B    = (const float*)d_in[0];
    const float* Bcat = (const float*)d_in[1];
    const float* Wh   = (const float*)d_in[2];
    const float* Whc  = (const float*)d_in[3];
    const float* bh   = (const float*)d_in[4];
    const float* Wv   = (const float*)d_in[5];
    const float* Wvc  = (const float*)d_in[6];
    const float* bv   = (const float*)d_in[7];
    const float* Wic  = (const float*)d_in[8];
    const float* Wicc = (const float*)d_in[9];
    const float* bic  = (const float*)d_in[10];
    float* out = (float*)d_out;

    // 512 blocks x 8 waves x 8 rows = 32768 rows; 4 blocks/CU (140KB LDS), 32 waves/CU
    hipLaunchKernelGGL(tpm_kernel, dim3(512), dim3(512), 0, stream,
                       B, Bcat, Wh, Whc, bh, Wv, Wvc, bv, Wic, Wicc, bic, out);
}

// Round 7
// 262.951 us; speedup vs baseline: 1.1772x; 1.1772x over previous
//
#include <hip/hip_runtime.h>

#define NCOMP 8
#define NCONT 56
#define NCAT 8
#define NU 100
#define NROWS 32768
#define SEPC 1e-3f
#define T1F 10.0f

// native type of __builtin_amdgcn_cvt_pkrtz / __builtin_amdgcn_fdot2 operands
typedef __fp16 f16x2 __attribute__((ext_vector_type(2)));
// arithmetic-friendly fp16 pair for the packed butterfly add
typedef _Float16 h2arith __attribute__((ext_vector_type(2)));

// One combined weight array: per feature f (0..55), 35 float4 "roles":
//  role 2c+t      : Wh comp c, k=8t..8t+7   (16 roles)
//  role 16+2c+t   : Wv comp c, k=8t..8t+7   (16 roles)
//  role 32+t      : Wic,       k=8t..8t+7   (2 roles)
//  role 34        : pad
#define FSTRIDE 35

union H8 { f16x2 h2[4]; float4 f4; };

__device__ __forceinline__ float sp(float x) {
    // softplus = ln2 * log2(1 + 2^(x*log2e)) via v_exp_f32/v_log_f32
    return 0.69314718f * __builtin_amdgcn_logf(1.0f + __builtin_amdgcn_exp2f(x * 1.44269504f));
}

__device__ __forceinline__ f16x2 pkrtz(float a, float b) {
    return __builtin_amdgcn_cvt_pkrtz(a, b);
}

__device__ __forceinline__ float fdot2(f16x2 a, f16x2 b, float c) {
    return __builtin_amdgcn_fdot2(a, b, c, false);
}

__device__ __forceinline__ h2arith h2shfl_xor(h2arith v, int off) {
    int i = __builtin_bit_cast(int, v);
    i = __shfl_xor(i, off, 64);
    return __builtin_bit_cast(h2arith, i);
}

// cap 128 VGPR — do NOT force 8 waves/EU: round 6 showed (512,8) makes the
// allocator spill to scratch (VGPR=32, 151 MB scratch writes). Natural
// footprint ~45-55 VGPR gives 8 waves/EU on its own.
__global__ __launch_bounds__(512, 4) void tpm_kernel(
    const float* __restrict__ B, const float* __restrict__ Bcat,
    const float* __restrict__ Wh, const float* __restrict__ Whc, const float* __restrict__ bh,
    const float* __restrict__ Wv, const float* __restrict__ Wvc, const float* __restrict__ bv,
    const float* __restrict__ Wic, const float* __restrict__ Wicc, const float* __restrict__ bic,
    float* __restrict__ out)
{
    __shared__ float4 sW[NCONT * FSTRIDE];  // 31360 B, f16 weights (H|V|IC)
    __shared__ float2 sBias[NCOMP];         // (sp(bh), sp(bv))
    __shared__ float  sBic;
    __shared__ int    sCode[8][4][NCAT];    // [wave][local row][cat feature]

    const int tid = threadIdx.x;

    // ---- stage Wh/Wv as f16: idx in [0,896) handles (icp = i*8+c, t) ----
    for (int idx = tid; idx < 896; idx += 512) {
        int icp = idx % 448, t = idx / 448;
        int i = icp >> 3, c = icp & 7;
        const float* gh = Wh + (size_t)(8 * t) * 448 + icp;
        const float* gv = Wv + (size_t)(8 * t) * 448 + icp;
        H8 uh, uv;
#pragma unroll
        for (int p = 0; p < 4; ++p) {
            uh.h2[p] = pkrtz(gh[(2 * p) * 448], gh[(2 * p + 1) * 448]);
            uv.h2[p] = pkrtz(gv[(2 * p) * 448], gv[(2 * p + 1) * 448]);
        }
        sW[i * FSTRIDE + 2 * c + t] = uh.f4;
        sW[i * FSTRIDE + 16 + 2 * c + t] = uv.f4;
    }
    if (tid < 112) {
        int i = tid % 56, t = tid / 56;
        const float* gi = Wic + (size_t)(8 * t) * 56 + i;
        H8 u;
#pragma unroll
        for (int p = 0; p < 4; ++p)
            u.h2[p] = pkrtz(gi[(2 * p) * 56], gi[(2 * p + 1) * 56]);
        sW[i * FSTRIDE + 32 + t] = u.f4;
    }
    if (tid < NCOMP) sBias[tid] = make_float2(sp(bh[tid]), sp(bv[tid]));
    if (tid == NCOMP) sBic = bic[0];
    __syncthreads();

    const int lane = tid & 63;
    const int widx = tid >> 6;      // 0..7
    const int s = lane & 15;        // sublane: feature group
    const int g = lane >> 4;        // row group 0..3
    const int R0 = (((blockIdx.x << 3) + widx) << 2);  // 4 rows per wave, exact cover
    const int r = R0 + g;           // this group's row

    // ---- full-wave cooperative one-hot scan of 4 rows (800 float4) ----
    {
        const float4* pc = (const float4*)(Bcat + (size_t)R0 * 800);
#pragma unroll
        for (int it = 0; it < 13; ++it) {
            int idx = it * 64 + lane;           // 0..831
            if (it < 12 || idx < 800) {
                int row = idx / 200;
                int pos = idx - row * 200;      // float4 within row
                float4 q = pc[idx];
                float n = (float)(4 * pos);
                float sc = q.x * (n + 1.0f) + q.y * (n + 2.0f) + q.z * (n + 3.0f) + q.w * (n + 4.0f);
                if (sc > 0.5f) {
                    int p = (int)sc - 1;        // element within row's 800
                    int f = p / NU;
                    sCode[widx][row][f] = p - f * NU;
                }
            }
        }
    }
    __threadfence_block();

    // ---- accumulators: 17 channels x 1 row ----
    float sh[NCOMP], sw[NCOMP];
    float ic = 0.0f;
#pragma unroll
    for (int c = 0; c < NCOMP; ++c) { sh[c] = sw[c] = 0.0f; }

    // ---- 4 passes: lane handles features s, s+16, s+32, s+48 ----
#pragma unroll 1
    for (int j = 0; j < 4; ++j) {
        int f = s + 16 * j;
        if (f < NCONT) {
            // continuous feature: basis for this row, dots against LDS weights
            const float4* pA = (const float4*)(B + (size_t)r * 896 + f * 16);
            float4 a0 = pA[0], a1 = pA[1], a2 = pA[2], a3 = pA[3];
            f16x2 ba[8];
            ba[0] = pkrtz(a0.x, a0.y); ba[1] = pkrtz(a0.z, a0.w);
            ba[2] = pkrtz(a1.x, a1.y); ba[3] = pkrtz(a1.z, a1.w);
            ba[4] = pkrtz(a2.x, a2.y); ba[5] = pkrtz(a2.z, a2.w);
            ba[6] = pkrtz(a3.x, a3.y); ba[7] = pkrtz(a3.z, a3.w);

            const float4* pw = sW + f * FSTRIDE;
#pragma unroll
            for (int c = 0; c < NCOMP; ++c) {
                H8 u0, u1, v0, v1;
                u0.f4 = pw[2 * c];      u1.f4 = pw[2 * c + 1];
                v0.f4 = pw[16 + 2 * c]; v1.f4 = pw[17 + 2 * c];
                float hA = 0.0f, vA = 0.0f;
#pragma unroll
                for (int p = 0; p < 4; ++p) {
                    hA = fdot2(ba[p], u0.h2[p], hA);
                    vA = fdot2(ba[p], v0.h2[p], vA);
                }
#pragma unroll
                for (int p = 0; p < 4; ++p) {
                    hA = fdot2(ba[4 + p], u1.h2[p], hA);
                    vA = fdot2(ba[4 + p], v1.h2[p], vA);
                }
                sh[c] += sp(hA);
                sw[c] += sp(vA);
            }
            {
                H8 i0, i1;
                i0.f4 = pw[32]; i1.f4 = pw[33];
                float iA = 0.0f;
#pragma unroll
                for (int p = 0; p < 4; ++p) iA = fdot2(ba[p], i0.h2[p], iA);
#pragma unroll
                for (int p = 0; p < 4; ++p) iA = fdot2(ba[4 + p], i1.h2[p], iA);
                ic += iA;   // IC has no softplus
            }
        } else {
            // categorical feature (pass 3, sublanes 8..15): fi = s-8
            int fi = s - 8;
            int cc = sCode[widx][g][fi];
            int gA = fi * NU + cc;
            const float4* qh = (const float4*)(Whc + gA * 8);
            const float4* qv = (const float4*)(Wvc + gA * 8);
            float4 h0 = qh[0], h1 = qh[1], v0 = qv[0], v1 = qv[1];
            sh[0] += sp(h0.x); sh[1] += sp(h0.y); sh[2] += sp(h0.z); sh[3] += sp(h0.w);
            sh[4] += sp(h1.x); sh[5] += sp(h1.y); sh[6] += sp(h1.z); sh[7] += sp(h1.w);
            sw[0] += sp(v0.x); sw[1] += sp(v0.y); sw[2] += sp(v0.z); sw[3] += sp(v0.w);
            sw[4] += sp(v1.x); sw[5] += sp(v1.y); sw[6] += sp(v1.z); sw[7] += sp(v1.w);
            ic += Wicc[gA];
        }
    }

    // ---- pack and 4-step butterfly within each 16-lane group ----
    h2arith hw[NCOMP];
#pragma unroll
    for (int c = 0; c < NCOMP; ++c)
        hw[c] = __builtin_bit_cast(h2arith, pkrtz(sh[c], sw[c]));
#pragma unroll
    for (int off = 8; off >= 1; off >>= 1) {
#pragma unroll
        for (int c = 0; c < NCOMP; ++c)
            hw[c] = hw[c] + h2shfl_xor(hw[c], off);
        ic += __shfl_xor(ic, off, 64);
    }

    // ---- sublanes 0..8 emit (t, x) for this group's row ----
    if (s < 9) {
        int m = (s == 8) ? 7 : s;
        float tj = SEPC * (float)s;
        float xj = ic + sBic;
#pragma unroll
        for (int c = 0; c < NCOMP; ++c) {
            float2 bb2 = sBias[c];
            if (c < m) tj += (float)hw[c][0] + bb2.x;
            if (c < s) {
                float vv = (float)hw[c][1] + bb2.y;
                xj += (c & 1) ? -vv : vv;
            }
        }
        if (s == 8) tj = fmaxf(tj, T1F);
        float2 o; o.x = tj; o.y = xj;
        ((float2*)out)[(size_t)r * 9 + s] = o;
    }
}

extern "C" void kernel_launch(void* const* d_in, const int* in_sizes, int n_in,
                              void* d_out, int out_size, void* d_ws, size_t ws_size,
                              hipStream_t stream) {
    (void)in_sizes; (void)n_in; (void)out_size; (void)d_ws; (void)ws_size;
    const float* B    = (const float*)d_in[0];
    const float* Bcat = (const float*)d_in[1];
    const float* Wh   = (const float*)d_in[2];
    const float* Whc  = (const float*)d_in[3];
    const float* bh   = (const float*)d_in[4];
    const float* Wv   = (const float*)d_in[5];
    const float* Wvc  = (const float*)d_in[6];
    const float* bv   = (const float*)d_in[7];
    const float* Wic  = (const float*)d_in[8];
    const float* Wicc = (const float*)d_in[9];
    const float* bic  = (const float*)d_in[10];
    float* out = (float*)d_out;

    // 1024 blocks x 8 waves x 4 rows = 32768 rows; 4 blocks/CU (33.7KB LDS),
    // 32 waves/CU resident (8192 waves total = 2 dispatch rounds of 4096? no:
    // 1024 blocks / 256 CUs = 4 blocks/CU, all co-resident).
    hipLaunchKernelGGL(tpm_kernel, dim3(1024), dim3(512), 0, stream,
                       B, Bcat, Wh, Whc, bh, Wv, Wvc, bv, Wic, Wicc, bic, out);
}

// Round 8
// 260.501 us; speedup vs baseline: 1.1882x; 1.0094x over previous
//
#include <hip/hip_runtime.h>

#define NCOMP 8
#define NCONT 56
#define NCAT 8
#define NU 100
#define NROWS 32768
#define SEPC 1e-3f
#define T1F 10.0f

// native type of __builtin_amdgcn_cvt_pkrtz / __builtin_amdgcn_fdot2 operands
typedef __fp16 f16x2 __attribute__((ext_vector_type(2)));
// arithmetic-friendly fp16 pair for the packed butterfly add
typedef _Float16 h2arith __attribute__((ext_vector_type(2)));

// One combined weight array: per feature f (0..55), 35 float4 "roles":
//  role 2c+t      : Wh comp c, k=8t..8t+7   (16 roles)
//  role 16+2c+t   : Wv comp c, k=8t..8t+7   (16 roles)
//  role 32+t      : Wic,       k=8t..8t+7   (2 roles)
//  role 34        : pad
#define FSTRIDE 35

union H8 { f16x2 h2[4]; float4 f4; };

__device__ __forceinline__ float sp(float x) {
    // softplus = ln2 * log2(1 + 2^(x*log2e)) via v_exp_f32/v_log_f32
    return 0.69314718f * __builtin_amdgcn_logf(1.0f + __builtin_amdgcn_exp2f(x * 1.44269504f));
}

__device__ __forceinline__ f16x2 pkrtz(float a, float b) {
    return __builtin_amdgcn_cvt_pkrtz(a, b);
}

__device__ __forceinline__ float fdot2(f16x2 a, f16x2 b, float c) {
    return __builtin_amdgcn_fdot2(a, b, c, false);
}

__device__ __forceinline__ h2arith h2shfl_xor(h2arith v, int off) {
    int i = __builtin_bit_cast(int, v);
    i = __shfl_xor(i, off, 64);
    return __builtin_bit_cast(h2arith, i);
}

// One continuous-feature accumulation against LDS weights.
__device__ __forceinline__ void acc_cont(const float4* __restrict__ pw,
                                         float4 a0, float4 a1, float4 a2, float4 a3,
                                         float* sh, float* sw, float& ic) {
    f16x2 ba[8];
    ba[0] = pkrtz(a0.x, a0.y); ba[1] = pkrtz(a0.z, a0.w);
    ba[2] = pkrtz(a1.x, a1.y); ba[3] = pkrtz(a1.z, a1.w);
    ba[4] = pkrtz(a2.x, a2.y); ba[5] = pkrtz(a2.z, a2.w);
    ba[6] = pkrtz(a3.x, a3.y); ba[7] = pkrtz(a3.z, a3.w);
#pragma unroll
    for (int c = 0; c < NCOMP; ++c) {
        H8 u0, u1, v0, v1;
        u0.f4 = pw[2 * c];      u1.f4 = pw[2 * c + 1];
        v0.f4 = pw[16 + 2 * c]; v1.f4 = pw[17 + 2 * c];
        float hA = 0.0f, vA = 0.0f;
#pragma unroll
        for (int p = 0; p < 4; ++p) {
            hA = fdot2(ba[p], u0.h2[p], hA);
            vA = fdot2(ba[p], v0.h2[p], vA);
        }
#pragma unroll
        for (int p = 0; p < 4; ++p) {
            hA = fdot2(ba[4 + p], u1.h2[p], hA);
            vA = fdot2(ba[4 + p], v1.h2[p], vA);
        }
        sh[c] += sp(hA);
        sw[c] += sp(vA);
    }
    H8 i0, i1;
    i0.f4 = pw[32]; i1.f4 = pw[33];
    float iA = 0.0f;
#pragma unroll
    for (int p = 0; p < 4; ++p) iA = fdot2(ba[p], i0.h2[p], iA);
#pragma unroll
    for (int p = 0; p < 4; ++p) iA = fdot2(ba[4 + p], i1.h2[p], iA);
    ic += iA;   // IC has no softplus
}

// cap 128 VGPR; do NOT force 8 waves/EU (round 6: (512,8) => scratch spill).
__global__ __launch_bounds__(512, 4) void tpm_kernel(
    const float* __restrict__ B, const float* __restrict__ Bcat,
    const float* __restrict__ Wh, const float* __restrict__ Whc, const float* __restrict__ bh,
    const float* __restrict__ Wv, const float* __restrict__ Wvc, const float* __restrict__ bv,
    const float* __restrict__ Wic, const float* __restrict__ Wicc, const float* __restrict__ bic,
    float* __restrict__ out)
{
    __shared__ float4 sW[NCONT * FSTRIDE];  // 31360 B, f16 weights (H|V|IC)
    __shared__ float2 sBias[NCOMP];         // (sp(bh), sp(bv))
    __shared__ float  sBic;
    __shared__ int    sCode[8][4][NCAT];    // [wave][local row][cat feature]

    const int tid = threadIdx.x;

    // ---- stage Wh/Wv as f16: idx in [0,896) handles (icp = i*8+c, t) ----
    for (int idx = tid; idx < 896; idx += 512) {
        int icp = idx % 448, t = idx / 448;
        int i = icp >> 3, c = icp & 7;
        const float* gh = Wh + (size_t)(8 * t) * 448 + icp;
        const float* gv = Wv + (size_t)(8 * t) * 448 + icp;
        H8 uh, uv;
#pragma unroll
        for (int p = 0; p < 4; ++p) {
            uh.h2[p] = pkrtz(gh[(2 * p) * 448], gh[(2 * p + 1) * 448]);
            uv.h2[p] = pkrtz(gv[(2 * p) * 448], gv[(2 * p + 1) * 448]);
        }
        sW[i * FSTRIDE + 2 * c + t] = uh.f4;
        sW[i * FSTRIDE + 16 + 2 * c + t] = uv.f4;
    }
    if (tid < 112) {
        int i = tid % 56, t = tid / 56;
        const float* gi = Wic + (size_t)(8 * t) * 56 + i;
        H8 u;
#pragma unroll
        for (int p = 0; p < 4; ++p)
            u.h2[p] = pkrtz(gi[(2 * p) * 56], gi[(2 * p + 1) * 56]);
        sW[i * FSTRIDE + 32 + t] = u.f4;
    }
    if (tid < NCOMP) sBias[tid] = make_float2(sp(bh[tid]), sp(bv[tid]));
    if (tid == NCOMP) sBic = bic[0];
    __syncthreads();

    const int lane = tid & 63;
    const int widx = tid >> 6;      // 0..7
    const int s = lane & 15;        // sublane: feature group
    const int g = lane >> 4;        // row group 0..3
    const int R0 = (((blockIdx.x << 3) + widx) << 2);  // 4 rows per wave, exact cover
    const int r = R0 + g;           // this group's row
    const float* browp = B + (size_t)r * 896;

    // ---- full-wave cooperative one-hot scan of 4 rows (800 float4) ----
    {
        const float4* pc = (const float4*)(Bcat + (size_t)R0 * 800);
#pragma unroll
        for (int it = 0; it < 13; ++it) {
            int idx = it * 64 + lane;           // 0..831
            if (it < 12 || idx < 800) {
                int row = idx / 200;
                int pos = idx - row * 200;      // float4 within row
                float4 q = pc[idx];
                float n = (float)(4 * pos);
                float sc = q.x * (n + 1.0f) + q.y * (n + 2.0f) + q.z * (n + 3.0f) + q.w * (n + 4.0f);
                if (sc > 0.5f) {
                    int p = (int)sc - 1;        // element within row's 800
                    int f = p / NU;
                    sCode[widx][row][f] = p - f * NU;
                }
            }
        }
    }
    __threadfence_block();

    // ---- prefetch the categorical gather NOW (used only in pass 3) ----
    float4 p3a, p3b, p3c, p3d;
    float p3ic = 0.0f;
    if (s >= 8) {
        int fi = s - 8;
        int cc = sCode[widx][g][fi];
        int gA = fi * NU + cc;
        const float4* qh = (const float4*)(Whc + gA * 8);
        const float4* qv = (const float4*)(Wvc + gA * 8);
        p3a = qh[0]; p3b = qh[1]; p3c = qv[0]; p3d = qv[1];
        p3ic = Wicc[gA];
    }

    // ---- accumulators: 17 channels x 1 row ----
    float sh[NCOMP], sw[NCOMP];
    float ic = 0.0f;
#pragma unroll
    for (int c = 0; c < NCOMP; ++c) { sh[c] = sw[c] = 0.0f; }

    // ---- prefetch pass-0 B data ----
    float4 cb0, cb1, cb2, cb3;
    {
        const float4* p = (const float4*)(browp + s * 16);
        cb0 = p[0]; cb1 = p[1]; cb2 = p[2]; cb3 = p[3];
    }

    // ---- passes 0..2 (all lanes continuous), pipelined ----
#pragma unroll
    for (int j = 0; j < 3; ++j) {
        float4 nb0, nb1, nb2, nb3;
        if (j < 2) {
            const float4* p = (const float4*)(browp + (s + 16 * (j + 1)) * 16);
            nb0 = p[0]; nb1 = p[1]; nb2 = p[2]; nb3 = p[3];
        } else {
            // pass-3 B data; clamp f for cat lanes (s>=8) to stay in-bounds,
            // their copy is discarded.
            int f3 = (s < 8) ? (s + 48) : 48;
            const float4* p = (const float4*)(browp + f3 * 16);
            nb0 = p[0]; nb1 = p[1]; nb2 = p[2]; nb3 = p[3];
        }
        acc_cont(sW + (s + 16 * j) * FSTRIDE, cb0, cb1, cb2, cb3, sh, sw, ic);
        cb0 = nb0; cb1 = nb1; cb2 = nb2; cb3 = nb3;
    }

    // ---- pass 3: cont for s<8 (buffered), cat for s>=8 (prefetched) ----
    if (s < 8) {
        acc_cont(sW + (s + 48) * FSTRIDE, cb0, cb1, cb2, cb3, sh, sw, ic);
    } else {
        sh[0] += sp(p3a.x); sh[1] += sp(p3a.y); sh[2] += sp(p3a.z); sh[3] += sp(p3a.w);
        sh[4] += sp(p3b.x); sh[5] += sp(p3b.y); sh[6] += sp(p3b.z); sh[7] += sp(p3b.w);
        sw[0] += sp(p3c.x); sw[1] += sp(p3c.y); sw[2] += sp(p3c.z); sw[3] += sp(p3c.w);
        sw[4] += sp(p3d.x); sw[5] += sp(p3d.y); sw[6] += sp(p3d.z); sw[7] += sp(p3d.w);
        ic += p3ic;
    }

    // ---- pack and 4-step butterfly within each 16-lane group ----
    h2arith hw[NCOMP];
#pragma unroll
    for (int c = 0; c < NCOMP; ++c)
        hw[c] = __builtin_bit_cast(h2arith, pkrtz(sh[c], sw[c]));
#pragma unroll
    for (int off = 8; off >= 1; off >>= 1) {
#pragma unroll
        for (int c = 0; c < NCOMP; ++c)
            hw[c] = hw[c] + h2shfl_xor(hw[c], off);
        ic += __shfl_xor(ic, off, 64);
    }

    // ---- sublanes 0..8 emit (t, x) for this group's row ----
    if (s < 9) {
        int m = (s == 8) ? 7 : s;
        float tj = SEPC * (float)s;
        float xj = ic + sBic;
#pragma unroll
        for (int c = 0; c < NCOMP; ++c) {
            float2 bb2 = sBias[c];
            if (c < m) tj += (float)hw[c][0] + bb2.x;
            if (c < s) {
                float vv = (float)hw[c][1] + bb2.y;
                xj += (c & 1) ? -vv : vv;
            }
        }
        if (s == 8) tj = fmaxf(tj, T1F);
        float2 o; o.x = tj; o.y = xj;
        ((float2*)out)[(size_t)r * 9 + s] = o;
    }
}

extern "C" void kernel_launch(void* const* d_in, const int* in_sizes, int n_in,
                              void* d_out, int out_size, void* d_ws, size_t ws_size,
                              hipStream_t stream) {
    (void)in_sizes; (void)n_in; (void)out_size; (void)d_ws; (void)ws_size;
    const float* B    = (const float*)d_in[0];
    const float* Bcat = (const float*)d_in[1];
    const float* Wh   = (const float*)d_in[2];
    const float* Whc  = (const float*)d_in[3];
    const float* bh   = (const float*)d_in[4];
    const float* Wv   = (const float*)d_in[5];
    const float* Wvc  = (const float*)d_in[6];
    const float* bv   = (const float*)d_in[7];
    const float* Wic  = (const float*)d_in[8];
    const float* Wicc = (const float*)d_in[9];
    const float* bic  = (const float*)d_in[10];
    float* out = (float*)d_out;

    // 1024 blocks x 8 waves x 4 rows = 32768 rows; 4 blocks/CU by LDS (33KB)
    hipLaunchKernelGGL(tpm_kernel, dim3(1024), dim3(512), 0, stream,
                       B, Bcat, Wh, Whc, bh, Wv, Wvc, bv, Wic, Wicc, bic, out);
}